// Round 19
// baseline (216.447 us; speedup 1.0000x reference)
//
#include <hip/hip_runtime.h>
#include <type_traits>

#define DIN  512
#define DHID 256
#define DOF  128

// CSR-build partitioning: node ranges of 8192, 32 blocks share each range's edges
#define RB   13
#define RSZ  (1 << RB)      // 8192 nodes per range
#define BPR  32             // blocks per range

typedef _Float16 f16;
typedef _Float16 f16x8 __attribute__((ext_vector_type(8)));
typedef float f32x4 __attribute__((ext_vector_type(4)));

__device__ inline void gload16(const void* g, void* l) {
    __builtin_amdgcn_global_load_lds(
        (const __attribute__((address_space(1))) void*)g,
        (__attribute__((address_space(3))) void*)l, 16, 0, 0);
}

// ---------------- per-(range,block) LDS histograms of src/dst ----------------
__global__ __launch_bounds__(256) void hist_deg(const int* __restrict__ src,
                                                const int* __restrict__ dst, int e,
                                                int* __restrict__ cnt_out,
                                                int* __restrict__ cnt_in) {
    __shared__ int h_out[RSZ], h_in[RSZ];
    const int r = blockIdx.x / BPR, b = blockIdx.x % BPR;
    const int base = r << RB;
    const int tid = threadIdx.x;
    for (int j = tid; j < RSZ; j += 256) { h_out[j] = 0; h_in[j] = 0; }
    __syncthreads();

    const int ce = (((e + BPR - 1) / BPR) + 3) & ~3;
    const int s0 = b * ce, s1 = min(s0 + ce, e);
    for (int i = s0 + tid * 4; i < s1; i += 1024) {
        if (i + 3 < s1) {
            int4 sv = *(const int4*)(src + i);
            int4 dv = *(const int4*)(dst + i);
            int v;
            v = sv.x - base; if ((unsigned)v < RSZ) atomicAdd(&h_out[v], 1);
            v = sv.y - base; if ((unsigned)v < RSZ) atomicAdd(&h_out[v], 1);
            v = sv.z - base; if ((unsigned)v < RSZ) atomicAdd(&h_out[v], 1);
            v = sv.w - base; if ((unsigned)v < RSZ) atomicAdd(&h_out[v], 1);
            v = dv.x - base; if ((unsigned)v < RSZ) atomicAdd(&h_in[v], 1);
            v = dv.y - base; if ((unsigned)v < RSZ) atomicAdd(&h_in[v], 1);
            v = dv.z - base; if ((unsigned)v < RSZ) atomicAdd(&h_in[v], 1);
            v = dv.w - base; if ((unsigned)v < RSZ) atomicAdd(&h_in[v], 1);
        } else {
            for (int q = i; q < s1; ++q) {
                int v = src[q] - base; if ((unsigned)v < RSZ) atomicAdd(&h_out[v], 1);
                v = dst[q] - base;     if ((unsigned)v < RSZ) atomicAdd(&h_in[v], 1);
            }
        }
    }
    __syncthreads();
    int* co = cnt_out + (size_t)(r * BPR + b) * RSZ;
    int* ci = cnt_in  + (size_t)(r * BPR + b) * RSZ;
    for (int j = tid; j < RSZ; j += 256) { co[j] = h_out[j]; ci[j] = h_in[j]; }
}

// ---------------- per-node: sum counts -> deg/norms; exclusive-scan cnt_in over b ----------------
__global__ void sum_base(const int* __restrict__ cnt_out, int* __restrict__ cnt_in,
                         int* __restrict__ deg_in,
                         float* __restrict__ norm_src, float* __restrict__ norm_dst, int n) {
    int d = blockIdx.x * blockDim.x + threadIdx.x;
    if (d >= n) return;
    const int r = d >> RB, j = d & (RSZ - 1);
    int* ci = cnt_in + (size_t)(r * BPR) * RSZ + j;
    int s = 0;
#pragma unroll 4
    for (int b = 0; b < BPR; ++b) {
        int c = ci[(size_t)b * RSZ];
        ci[(size_t)b * RSZ] = s;          // in-place exclusive base
        s += c;
    }
    deg_in[d] = s;
    norm_dst[d] = rsqrtf(fmaxf((float)s, 1.0f));
    const int* co = cnt_out + (size_t)(r * BPR) * RSZ + j;
    int s2 = 0;
#pragma unroll 4
    for (int b = 0; b < BPR; ++b) s2 += co[(size_t)b * RSZ];
    norm_src[d] = rsqrtf(fmaxf((float)s2, 1.0f));
}

// ---------------- two-level exclusive scan: deg_in -> rowptr[n+1] ----------------
__global__ __launch_bounds__(256) void scan_part(const int* __restrict__ deg,
                                                 int* __restrict__ partial, int n) {
    const int base = blockIdx.x * 1024;
    const int tid = threadIdx.x;
    int v = 0;
#pragma unroll
    for (int j = 0; j < 4; ++j) {
        int i = base + tid * 4 + j;
        if (i < n) v += deg[i];
    }
    for (int o = 1; o < 64; o <<= 1) v += __shfl_xor(v, o);
    __shared__ int wsum[4];
    if ((tid & 63) == 0) wsum[tid >> 6] = v;
    __syncthreads();
    if (tid == 0) partial[blockIdx.x] = wsum[0] + wsum[1] + wsum[2] + wsum[3];
}

__global__ __launch_bounds__(64) void scan_offsets(int* __restrict__ partial, int nb,
                                                   int* __restrict__ rowptr, int n) {
    const int l = threadIdx.x;
    int orig = (l < nb) ? partial[l] : 0;
    int v = orig;
    for (int o = 1; o < 64; o <<= 1) {
        int u = __shfl_up(v, o);
        if (l >= o) v += u;
    }
    if (l < nb) partial[l] = v - orig;        // exclusive
    if (l == nb - 1) rowptr[n] = v;           // total edge count
}

__global__ __launch_bounds__(256) void scan_apply(const int* __restrict__ deg,
                                                  const int* __restrict__ partial,
                                                  int* __restrict__ rowptr, int n) {
    const int base = blockIdx.x * 1024;
    const int tid = threadIdx.x;
    int x[4]; int s = 0;
#pragma unroll
    for (int j = 0; j < 4; ++j) {
        int i = base + tid * 4 + j;
        x[j] = (i < n) ? deg[i] : 0;
        s += x[j];
    }
    const int l = tid & 63, w = tid >> 6;
    int inc = s;
    for (int o = 1; o < 64; o <<= 1) {
        int u = __shfl_up(inc, o);
        if (l >= o) inc += u;
    }
    __shared__ int wsum[4];
    if (l == 63) wsum[w] = inc;
    __syncthreads();
    int wbase = 0;
    for (int q = 0; q < w; ++q) wbase += wsum[q];
    int excl = partial[blockIdx.x] + wbase + (inc - s);
#pragma unroll
    for (int j = 0; j < 4; ++j) {
        int i = base + tid * 4 + j;
        if (i < n) rowptr[i] = excl;
        excl += x[j];
    }
}

// ---------------- fill csr_src: LDS cursors only, no global atomics ----------------
__global__ __launch_bounds__(256) void fill_csr2(const int* __restrict__ src,
                                                 const int* __restrict__ dst, int e,
                                                 const int* __restrict__ rowptr,
                                                 const int* __restrict__ base_in,
                                                 int* __restrict__ csr_src) {
    __shared__ int cur[RSZ];
    const int r = blockIdx.x / BPR, b = blockIdx.x % BPR;
    const int base = r << RB;
    const int tid = threadIdx.x;
    for (int j = tid; j < RSZ; j += 256) cur[j] = 0;
    __syncthreads();

    const int* bi = base_in + (size_t)(r * BPR + b) * RSZ;
    const int ce = (((e + BPR - 1) / BPR) + 3) & ~3;
    const int s0 = b * ce, s1 = min(s0 + ce, e);
    for (int i = s0 + tid * 4; i < s1; i += 1024) {
        if (i + 3 < s1) {
            int4 dv = *(const int4*)(dst + i);
            int4 sv = *(const int4*)(src + i);
            int v;
            v = dv.x - base; if ((unsigned)v < RSZ) { int p = atomicAdd(&cur[v], 1); csr_src[rowptr[base + v] + bi[v] + p] = sv.x; }
            v = dv.y - base; if ((unsigned)v < RSZ) { int p = atomicAdd(&cur[v], 1); csr_src[rowptr[base + v] + bi[v] + p] = sv.y; }
            v = dv.z - base; if ((unsigned)v < RSZ) { int p = atomicAdd(&cur[v], 1); csr_src[rowptr[base + v] + bi[v] + p] = sv.z; }
            v = dv.w - base; if ((unsigned)v < RSZ) { int p = atomicAdd(&cur[v], 1); csr_src[rowptr[base + v] + bi[v] + p] = sv.w; }
        } else {
            for (int q = i; q < s1; ++q) {
                int v = dst[q] - base;
                if ((unsigned)v < RSZ) { int p = atomicAdd(&cur[v], 1); csr_src[rowptr[base + v] + bi[v] + p] = src[q]; }
            }
        }
    }
}

// ---------------- W -> f16 transposed: wt[c][k] = (f16)W[k][c] ----------------
__global__ void transpose_w(const float* __restrict__ W1, const float* __restrict__ W2,
                            f16* __restrict__ w1t, f16* __restrict__ w2t) {
    int t = blockIdx.x * blockDim.x + threadIdx.x;
    if (t < DIN * DHID) {
        int k = t / DHID, c = t % DHID;
        w1t[c * DIN + k] = (f16)W1[t];
    } else {
        int u = t - DIN * DHID;
        if (u < DHID * DOF) {
            int k = u / DOF, c = u % DOF;
            w2t[c * DHID + k] = (f16)W2[u];
        }
    }
}

// ---------------- MFMA GEMM layer-1, BM=128, 3-tile prefetch (R13 measured-best) ----------------
template<int K, int N, bool A_F32>
__global__ __launch_bounds__(256) void mfma_gemm(const void* __restrict__ Aptr,
                                                 const float* __restrict__ norm,
                                                 const f16* __restrict__ Bt,
                                                 f16* __restrict__ H, int M) {
    constexpr int BM = 128, BN = 128, BK = 32;
    constexpr int NT = K / BK;
    __shared__ __align__(16) f16 smem[BM * BN];      // 32KB

    const int rbase = blockIdx.x * BM;
    const int nbj = blockIdx.y * BN;
    const int tid = threadIdx.x;
    const int l = tid & 63, wid = tid >> 6;
    const int wr = wid >> 1, wc = wid & 1;
    const int fr = l & 15, kg = l >> 4;

    int arow[2], achk[2];
    float ascale[2];
#pragma unroll
    for (int j = 0; j < 2; ++j) {
        int u = tid + j * 256;
        arow[j] = u >> 2; achk[j] = u & 3;
        if (A_F32) {
            int grow = rbase + arow[j];
            ascale[j] = (grow < M) ? norm[grow] : 0.0f;
        }
    }

    struct ABregs {
        float4 a0[2], a1[2];
        f16x8  a16[2];
        f16x8  b[2];
    };

    auto gload = [&](int k0) {
        ABregs r;
#pragma unroll
        for (int j = 0; j < 2; ++j) {
            int grow = rbase + arow[j];
            if (A_F32) {
                if (grow < M) {
                    const float* A = (const float*)Aptr + (long)grow * K + k0 + achk[j] * 8;
                    r.a0[j] = *(const float4*)A;
                    r.a1[j] = *(const float4*)(A + 4);
                } else {
                    r.a0[j] = make_float4(0.f, 0.f, 0.f, 0.f);
                    r.a1[j] = make_float4(0.f, 0.f, 0.f, 0.f);
                }
            } else {
                f16x8 v = {};
                if (grow < M)
                    v = *(const f16x8*)((const f16*)Aptr + (long)grow * K + k0 + achk[j] * 8);
                r.a16[j] = v;
            }
            r.b[j] = *(const f16x8*)(Bt + (long)(nbj + arow[j]) * K + k0 + achk[j] * 8);
        }
        return r;
    };

    auto swrite = [&](int buf, const ABregs& r) {
        f16* As = smem + buf * 8192;
        f16* Bs = As + 4096;
#pragma unroll
        for (int j = 0; j < 2; ++j) {
            f16x8 v;
            if (A_F32) {
                float s = ascale[j];
                v[0] = (f16)(r.a0[j].x * s); v[1] = (f16)(r.a0[j].y * s);
                v[2] = (f16)(r.a0[j].z * s); v[3] = (f16)(r.a0[j].w * s);
                v[4] = (f16)(r.a1[j].x * s); v[5] = (f16)(r.a1[j].y * s);
                v[6] = (f16)(r.a1[j].z * s); v[7] = (f16)(r.a1[j].w * s);
            } else {
                v = r.a16[j];
            }
            int ia = (arow[j] * BK + achk[j] * 8) ^ ((arow[j] & 7) << 3);
            *(f16x8*)&As[ia] = v;
            *(f16x8*)&Bs[ia] = r.b[j];
        }
    };

    f32x4 acc[4][4] = {};

    auto compute = [&](int buf) {
        const f16* As = smem + buf * 8192;
        const f16* Bs = As + 4096;
        f16x8 af[4], bf[4];
#pragma unroll
        for (int m = 0; m < 4; ++m) {
            int row = wr * 64 + m * 16 + fr;
            int ia = (row * BK + kg * 8) ^ ((row & 7) << 3);
            af[m] = *(const f16x8*)&As[ia];
        }
#pragma unroll
        for (int nf = 0; nf < 4; ++nf) {
            int c = wc * 64 + nf * 16 + fr;
            int ib = (c * BK + kg * 8) ^ ((c & 7) << 3);
            bf[nf] = *(const f16x8*)&Bs[ib];
        }
#pragma unroll
        for (int m = 0; m < 4; ++m)
#pragma unroll
            for (int nf = 0; nf < 4; ++nf)
                acc[m][nf] = __builtin_amdgcn_mfma_f32_16x16x32_f16(af[m], bf[nf], acc[m][nf], 0, 0, 0);
    };

    ABregs rb, rc;
    {
        ABregs ra = gload(0);
        swrite(0, ra);
        rb = gload(BK);
        if (NT > 2) rc = gload(2 * BK);
    }

#pragma unroll
    for (int kt = 0; kt < NT; kt += 2) {
        __syncthreads();
        compute(0);
        if (kt + 1 < NT) swrite(1, rb);
        if (kt + 3 < NT) rb = gload((kt + 3) * BK);
        if (kt + 1 < NT) {
            __syncthreads();
            compute(1);
            if (kt + 2 < NT) swrite(0, rc);
            if (kt + 4 < NT) rc = gload((kt + 4) * BK);
        }
    }

    __syncthreads();
#pragma unroll
    for (int m = 0; m < 4; ++m)
#pragma unroll
        for (int nf = 0; nf < 4; ++nf)
#pragma unroll
            for (int i = 0; i < 4; ++i) {
                int row = wr * 64 + m * 16 + (l >> 4) * 4 + i;
                int col = wc * 64 + nf * 16 + (l & 15);
                smem[row * BN + col] = (f16)acc[m][nf][i];
            }
    __syncthreads();
#pragma unroll
    for (int j = 0; j < 8; ++j) {
        int u = tid + j * 256;
        int row = u >> 4, cu = u & 15;
        int grow = rbase + row;
        if (grow < M)
            *(f16x8*)(H + (long)grow * N + nbj + cu * 8) =
                *(const f16x8*)&smem[row * BN + cu * 8];
    }
}

// ---------------- all-f16 MFMA GEMM with global_load_lds staging (layer 2) ----------------
// A: f16 [mpad][K] (rows >= M are readable garbage -> discarded output). Bt: f16 [N][K].
// BM=BN=128, BK=32, 4 waves; LDS 32KB linear; validated for correctness in R16.
template<int K, int N>
__global__ __launch_bounds__(256) void mfma_gemm16(const f16* __restrict__ A,
                                                   const f16* __restrict__ Bt,
                                                   f16* __restrict__ H, int M) {
    constexpr int BK = 32, NT = K / BK;
    __shared__ __align__(16) f16 smem[16384];        // 32KB
    const int rbase = blockIdx.x * 128;
    const int nbj = blockIdx.y * 128;
    const int tid = threadIdx.x;
    const int l = tid & 63, wid = tid >> 6;
    const int wr = wid >> 1, wc = wid & 1;
    const int fr = l & 15, kg = l >> 4;

    const int slot0 = wid * 2;
    const int srow = l >> 2, skch = l & 3;

    auto stage = [&](int buf, int k0) {
        f16* As = smem + buf * 8192;
        f16* Bs = As + 4096;
#pragma unroll
        for (int q = 0; q < 2; ++q) {
            int slot = slot0 + q;
            int row = slot * 16 + srow;
            const f16* ga = A + (long)(rbase + row) * K + k0 + skch * 8;
            gload16(ga, As + slot * 512);
            const f16* gb = Bt + (long)(nbj + row) * K + k0 + skch * 8;
            gload16(gb, Bs + slot * 512);
        }
    };

    f32x4 acc[4][4] = {};

    auto compute = [&](int buf) {
        const f16* As = smem + buf * 8192;
        const f16* Bs = As + 4096;
        f16x8 af[4], bf[4];
#pragma unroll
        for (int m = 0; m < 4; ++m)
            af[m] = *(const f16x8*)&As[(wr * 64 + m * 16 + fr) * 32 + kg * 8];
#pragma unroll
        for (int nf = 0; nf < 4; ++nf)
            bf[nf] = *(const f16x8*)&Bs[(wc * 64 + nf * 16 + fr) * 32 + kg * 8];
#pragma unroll
        for (int m = 0; m < 4; ++m)
#pragma unroll
            for (int nf = 0; nf < 4; ++nf)
                acc[m][nf] = __builtin_amdgcn_mfma_f32_16x16x32_f16(af[m], bf[nf], acc[m][nf], 0, 0, 0);
    };

    stage(0, 0);
    __syncthreads();
    int buf = 0;
    for (int kt = 0; kt < NT; ++kt) {
        if (kt + 1 < NT) stage(buf ^ 1, (kt + 1) * BK);
        compute(buf);
        __syncthreads();
        buf ^= 1;
    }

#pragma unroll
    for (int m = 0; m < 4; ++m)
#pragma unroll
        for (int nf = 0; nf < 4; ++nf)
#pragma unroll
            for (int i = 0; i < 4; ++i) {
                int row = wr * 64 + m * 16 + (l >> 4) * 4 + i;
                int col = wc * 64 + nf * 16 + (l & 15);
                smem[row * 128 + col] = (f16)acc[m][nf][i];
            }
    __syncthreads();
#pragma unroll
    for (int j = 0; j < 8; ++j) {
        int u = tid + j * 256;
        int row = u >> 4, cu = u & 15;
        int grow = rbase + row;
        if (grow < M)
            *(f16x8*)(H + (long)grow * N + nbj + cu * 8) =
                *(const f16x8*)&smem[row * 128 + cu * 8];
    }
}

// ---------------- multi-edge vectorized CSR aggregate, 8-deep bursts ----------------
// One wave per node. LR = F/8 lanes cover one row (f16x8); EPW = 64/LR edges per
// wave-instr. 8-instr bursts (8*EPW edges in flight), then 2-instr, then clamped tail.
template<int F, bool RELU, bool FOLD, bool OUT_F16>
__global__ __launch_bounds__(256) void aggregate_vec(const f16* __restrict__ H,
                                                     const int* __restrict__ rowptr,
                                                     const int* __restrict__ csr_src,
                                                     const float* __restrict__ norm_dst,
                                                     const float* __restrict__ norm_src,
                                                     const float* __restrict__ bias,
                                                     void* __restrict__ outp, int n) {
    constexpr int LR = F / 8;          // lanes per row: 32 (F=256), 16 (F=128)
    constexpr int EPW = 64 / LR;       // edges per wave-instr: 2, 4

    const int node = blockIdx.x * 4 + (threadIdx.x >> 6);
    if (node >= n) return;
    const int l = threadIdx.x & 63;
    const int slot = l / LR;
    const int col = (l & (LR - 1)) * 8;
    const f16* __restrict__ Hc = H + col;

    int k = rowptr[node];
    const int end = rowptr[node + 1];

    float acc[8] = {};
    // 8-instruction bursts: 8*EPW edges, no guards
    for (; k + 8 * EPW <= end; k += 8 * EPW) {
        int id[8];
#pragma unroll
        for (int b = 0; b < 8; ++b) id[b] = csr_src[k + b * EPW + slot];
        f16x8 v[8];
#pragma unroll
        for (int b = 0; b < 8; ++b) v[b] = *(const f16x8*)(Hc + (long)id[b] * F);
#pragma unroll
        for (int b = 0; b < 8; ++b)
#pragma unroll
            for (int q = 0; q < 8; ++q) acc[q] += (float)v[b][q];
    }
    // 2-instruction batches
    for (; k + 2 * EPW <= end; k += 2 * EPW) {
        int i0 = csr_src[k + slot];
        int i1 = csr_src[k + EPW + slot];
        f16x8 v0 = *(const f16x8*)(Hc + (long)i0 * F);
        f16x8 v1 = *(const f16x8*)(Hc + (long)i1 * F);
#pragma unroll
        for (int q = 0; q < 8; ++q) acc[q] += (float)v0[q];
#pragma unroll
        for (int q = 0; q < 8; ++q) acc[q] += (float)v1[q];
    }
    // tail: guarded per wave-instruction (clamped index keeps load in-bounds)
    for (; k < end; k += EPW) {
        int idx = k + slot;
        int ci = min(idx, end - 1);
        int s = csr_src[ci];
        f16x8 v = *(const f16x8*)(Hc + (long)s * F);
        if (idx < end) {
#pragma unroll
            for (int q = 0; q < 8; ++q) acc[q] += (float)v[q];
        }
    }

    // combine slot partial sums
#pragma unroll
    for (int o = LR; o < 64; o <<= 1) {
#pragma unroll
        for (int q = 0; q < 8; ++q) acc[q] += __shfl_xor(acc[q], o);
    }

    const float nd = norm_dst[node];
    const float ns = FOLD ? norm_src[node] : 1.0f;
#pragma unroll
    for (int q = 0; q < 8; ++q) {
        float v = acc[q] * nd + bias[col + q];
        if (RELU) v = fmaxf(v, 0.0f);
        acc[q] = v * ns;
    }

    if (slot == 0) {
        if (OUT_F16) {
            f16x8 o;
#pragma unroll
            for (int q = 0; q < 8; ++q) o[q] = (f16)acc[q];
            *(f16x8*)((f16*)outp + (long)node * F + col) = o;
        } else {
            float* op = (float*)outp + (long)node * F + col;
            *(float4*)op = make_float4(acc[0], acc[1], acc[2], acc[3]);
            *(float4*)(op + 4) = make_float4(acc[4], acc[5], acc[6], acc[7]);
        }
    }
}

extern "C" void kernel_launch(void* const* d_in, const int* in_sizes, int n_in,
                              void* d_out, int out_size, void* d_ws, size_t ws_size,
                              hipStream_t stream) {
    const float* features = (const float*)d_in[0];
    const int*   src      = (const int*)d_in[1];
    const int*   dst      = (const int*)d_in[2];
    const float* W1       = (const float*)d_in[3];
    const float* b1       = (const float*)d_in[4];
    const float* W2       = (const float*)d_in[5];
    const float* b2       = (const float*)d_in[6];
    float* out = (float*)d_out;

    const int n = in_sizes[0] / DIN;          // 50000
    const int e = in_sizes[1];                // 800000
    const int mpad = (n + 127) & ~127;        // 50048

    const int ranges = (n + RSZ - 1) >> RB;            // 7
    const size_t cntsz = (size_t)ranges * BPR * RSZ;

    // ---- workspace layout ----
    char* ws = (char*)d_ws;
    size_t off = 0;
    auto alloc = [&](size_t bytes) { size_t o = off; off += (bytes + 255) & ~(size_t)255; return o; };
    size_t o_degi   = alloc((size_t)n * 4);            // deg_in
    size_t o_nsrc   = alloc((size_t)n * 4);            // norm_src
    size_t o_ndst   = alloc((size_t)n * 4);            // norm_dst
    size_t o_rowptr = alloc((size_t)(n + 1) * 4);      // rowptr
    size_t o_part   = alloc((size_t)64 * 4);           // scan partials
    size_t o_csr    = alloc((size_t)e * 4);            // csr_src
    size_t o_cnto   = alloc(cntsz * 4);                // cnt_out
    size_t o_cnti   = alloc(cntsz * 4);                // cnt_in -> base_in
    size_t o_w1t    = alloc((size_t)DIN * DHID * 2);   // W1^T f16
    size_t o_w2t    = alloc((size_t)DHID * DOF * 2);   // W2^T f16
    size_t o_h1     = alloc((size_t)n * DHID * 2);     // h1 f16
    size_t o_x1     = alloc((size_t)mpad * DHID * 2);  // x1 f16 padded (pad rows: stale, discarded)
    size_t o_h2     = alloc((size_t)n * DOF * 2);      // h2 f16
    (void)ws_size;

    int*   deg_in   = (int*)(ws + o_degi);
    float* norm_src = (float*)(ws + o_nsrc);
    float* norm_dst = (float*)(ws + o_ndst);
    int*   rowptr   = (int*)(ws + o_rowptr);
    int*   partial  = (int*)(ws + o_part);
    int*   csr_src  = (int*)(ws + o_csr);
    int*   cnt_out  = (int*)(ws + o_cnto);
    int*   cnt_in   = (int*)(ws + o_cnti);
    f16*   w1t      = (f16*)(ws + o_w1t);
    f16*   w2t      = (f16*)(ws + o_w2t);
    f16*   h1       = (f16*)(ws + o_h1);
    f16*   x1       = (f16*)(ws + o_x1);
    f16*   h2       = (f16*)(ws + o_h2);

    // ---- graph preprocessing (no global atomics, no memsets) ----
    const int hblocks = ranges * BPR;                  // 224
    hist_deg<<<hblocks, 256, 0, stream>>>(src, dst, e, cnt_out, cnt_in);
    sum_base<<<(n + 255) / 256, 256, 0, stream>>>(cnt_out, cnt_in, deg_in,
                                                  norm_src, norm_dst, n);
    const int nb = (n + 1023) / 1024;                  // 49
    scan_part<<<nb, 256, 0, stream>>>(deg_in, partial, n);
    scan_offsets<<<1, 64, 0, stream>>>(partial, nb, rowptr, n);
    scan_apply<<<nb, 256, 0, stream>>>(deg_in, partial, rowptr, n);
    fill_csr2<<<hblocks, 256, 0, stream>>>(src, dst, e, rowptr, cnt_in, csr_src);
    transpose_w<<<(DIN * DHID + DHID * DOF + 255) / 256, 256, 0, stream>>>(W1, W2, w1t, w2t);

    const int mtiles = (n + 127) / 128;      // 391
    const int ablocks = (n + 3) / 4;         // 4 nodes (waves) per 256-thr block

    // ---- layer 1 ----
    mfma_gemm<DIN, DHID, true><<<dim3(mtiles, DHID / 128), 256, 0, stream>>>(
        features, norm_src, w1t, h1, n);
    aggregate_vec<DHID, true, true, true><<<ablocks, 256, 0, stream>>>(
        h1, rowptr, csr_src, norm_dst, norm_src, b1, x1, n);

    // ---- layer 2 (gload_lds GEMM: x1 already f16, no conversion pass needed) ----
    mfma_gemm16<DHID, DOF><<<dim3(mpad / 128, DOF / 128), 256, 0, stream>>>(x1, w2t, h2, n);
    aggregate_vec<DOF, false, false, false><<<ablocks, 256, 0, stream>>>(
        h2, rowptr, csr_src, norm_dst, norm_src, b2, out, n);
}

// Round 20
// 210.147 us; speedup vs baseline: 1.0300x; 1.0300x over previous
//
#include <hip/hip_runtime.h>
#include <type_traits>

#define DIN  512
#define DHID 256
#define DOF  128

// CSR-build partitioning: node ranges of 8192, 32 blocks share each range's edges
#define RB   13
#define RSZ  (1 << RB)      // 8192 nodes per range
#define BPR  32             // blocks per range

typedef _Float16 f16;
typedef _Float16 f16x8 __attribute__((ext_vector_type(8)));
typedef float f32x4 __attribute__((ext_vector_type(4)));

// ---------------- per-(range,block) LDS histograms of src/dst ----------------
__global__ __launch_bounds__(256) void hist_deg(const int* __restrict__ src,
                                                const int* __restrict__ dst, int e,
                                                int* __restrict__ cnt_out,
                                                int* __restrict__ cnt_in) {
    __shared__ int h_out[RSZ], h_in[RSZ];
    const int r = blockIdx.x / BPR, b = blockIdx.x % BPR;
    const int base = r << RB;
    const int tid = threadIdx.x;
    for (int j = tid; j < RSZ; j += 256) { h_out[j] = 0; h_in[j] = 0; }
    __syncthreads();

    const int ce = (((e + BPR - 1) / BPR) + 3) & ~3;
    const int s0 = b * ce, s1 = min(s0 + ce, e);
    for (int i = s0 + tid * 4; i < s1; i += 1024) {
        if (i + 3 < s1) {
            int4 sv = *(const int4*)(src + i);
            int4 dv = *(const int4*)(dst + i);
            int v;
            v = sv.x - base; if ((unsigned)v < RSZ) atomicAdd(&h_out[v], 1);
            v = sv.y - base; if ((unsigned)v < RSZ) atomicAdd(&h_out[v], 1);
            v = sv.z - base; if ((unsigned)v < RSZ) atomicAdd(&h_out[v], 1);
            v = sv.w - base; if ((unsigned)v < RSZ) atomicAdd(&h_out[v], 1);
            v = dv.x - base; if ((unsigned)v < RSZ) atomicAdd(&h_in[v], 1);
            v = dv.y - base; if ((unsigned)v < RSZ) atomicAdd(&h_in[v], 1);
            v = dv.z - base; if ((unsigned)v < RSZ) atomicAdd(&h_in[v], 1);
            v = dv.w - base; if ((unsigned)v < RSZ) atomicAdd(&h_in[v], 1);
        } else {
            for (int q = i; q < s1; ++q) {
                int v = src[q] - base; if ((unsigned)v < RSZ) atomicAdd(&h_out[v], 1);
                v = dst[q] - base;     if ((unsigned)v < RSZ) atomicAdd(&h_in[v], 1);
            }
        }
    }
    __syncthreads();
    int* co = cnt_out + (size_t)(r * BPR + b) * RSZ;
    int* ci = cnt_in  + (size_t)(r * BPR + b) * RSZ;
    for (int j = tid; j < RSZ; j += 256) { co[j] = h_out[j]; ci[j] = h_in[j]; }
}

// ---------------- per-node: sum counts -> deg/norms; exclusive-scan cnt_in over b ----------------
__global__ void sum_base(const int* __restrict__ cnt_out, int* __restrict__ cnt_in,
                         int* __restrict__ deg_in,
                         float* __restrict__ norm_src, float* __restrict__ norm_dst, int n) {
    int d = blockIdx.x * blockDim.x + threadIdx.x;
    if (d >= n) return;
    const int r = d >> RB, j = d & (RSZ - 1);
    int* ci = cnt_in + (size_t)(r * BPR) * RSZ + j;
    int s = 0;
#pragma unroll 4
    for (int b = 0; b < BPR; ++b) {
        int c = ci[(size_t)b * RSZ];
        ci[(size_t)b * RSZ] = s;          // in-place exclusive base
        s += c;
    }
    deg_in[d] = s;
    norm_dst[d] = rsqrtf(fmaxf((float)s, 1.0f));
    const int* co = cnt_out + (size_t)(r * BPR) * RSZ + j;
    int s2 = 0;
#pragma unroll 4
    for (int b = 0; b < BPR; ++b) s2 += co[(size_t)b * RSZ];
    norm_src[d] = rsqrtf(fmaxf((float)s2, 1.0f));
}

// ---------------- two-level exclusive scan: deg_in -> rowptr[n+1] ----------------
__global__ __launch_bounds__(256) void scan_part(const int* __restrict__ deg,
                                                 int* __restrict__ partial, int n) {
    const int base = blockIdx.x * 1024;
    const int tid = threadIdx.x;
    int v = 0;
#pragma unroll
    for (int j = 0; j < 4; ++j) {
        int i = base + tid * 4 + j;
        if (i < n) v += deg[i];
    }
    for (int o = 1; o < 64; o <<= 1) v += __shfl_xor(v, o);
    __shared__ int wsum[4];
    if ((tid & 63) == 0) wsum[tid >> 6] = v;
    __syncthreads();
    if (tid == 0) partial[blockIdx.x] = wsum[0] + wsum[1] + wsum[2] + wsum[3];
}

__global__ __launch_bounds__(64) void scan_offsets(int* __restrict__ partial, int nb,
                                                   int* __restrict__ rowptr, int n) {
    const int l = threadIdx.x;
    int orig = (l < nb) ? partial[l] : 0;
    int v = orig;
    for (int o = 1; o < 64; o <<= 1) {
        int u = __shfl_up(v, o);
        if (l >= o) v += u;
    }
    if (l < nb) partial[l] = v - orig;        // exclusive
    if (l == nb - 1) rowptr[n] = v;           // total edge count
}

__global__ __launch_bounds__(256) void scan_apply(const int* __restrict__ deg,
                                                  const int* __restrict__ partial,
                                                  int* __restrict__ rowptr, int n) {
    const int base = blockIdx.x * 1024;
    const int tid = threadIdx.x;
    int x[4]; int s = 0;
#pragma unroll
    for (int j = 0; j < 4; ++j) {
        int i = base + tid * 4 + j;
        x[j] = (i < n) ? deg[i] : 0;
        s += x[j];
    }
    const int l = tid & 63, w = tid >> 6;
    int inc = s;
    for (int o = 1; o < 64; o <<= 1) {
        int u = __shfl_up(inc, o);
        if (l >= o) inc += u;
    }
    __shared__ int wsum[4];
    if (l == 63) wsum[w] = inc;
    __syncthreads();
    int wbase = 0;
    for (int q = 0; q < w; ++q) wbase += wsum[q];
    int excl = partial[blockIdx.x] + wbase + (inc - s);
#pragma unroll
    for (int j = 0; j < 4; ++j) {
        int i = base + tid * 4 + j;
        if (i < n) rowptr[i] = excl;
        excl += x[j];
    }
}

// ---------------- fill csr_src: LDS cursors only, no global atomics ----------------
__global__ __launch_bounds__(256) void fill_csr2(const int* __restrict__ src,
                                                 const int* __restrict__ dst, int e,
                                                 const int* __restrict__ rowptr,
                                                 const int* __restrict__ base_in,
                                                 int* __restrict__ csr_src) {
    __shared__ int cur[RSZ];
    const int r = blockIdx.x / BPR, b = blockIdx.x % BPR;
    const int base = r << RB;
    const int tid = threadIdx.x;
    for (int j = tid; j < RSZ; j += 256) cur[j] = 0;
    __syncthreads();

    const int* bi = base_in + (size_t)(r * BPR + b) * RSZ;
    const int ce = (((e + BPR - 1) / BPR) + 3) & ~3;
    const int s0 = b * ce, s1 = min(s0 + ce, e);
    for (int i = s0 + tid * 4; i < s1; i += 1024) {
        if (i + 3 < s1) {
            int4 dv = *(const int4*)(dst + i);
            int4 sv = *(const int4*)(src + i);
            int v;
            v = dv.x - base; if ((unsigned)v < RSZ) { int p = atomicAdd(&cur[v], 1); csr_src[rowptr[base + v] + bi[v] + p] = sv.x; }
            v = dv.y - base; if ((unsigned)v < RSZ) { int p = atomicAdd(&cur[v], 1); csr_src[rowptr[base + v] + bi[v] + p] = sv.y; }
            v = dv.z - base; if ((unsigned)v < RSZ) { int p = atomicAdd(&cur[v], 1); csr_src[rowptr[base + v] + bi[v] + p] = sv.z; }
            v = dv.w - base; if ((unsigned)v < RSZ) { int p = atomicAdd(&cur[v], 1); csr_src[rowptr[base + v] + bi[v] + p] = sv.w; }
        } else {
            for (int q = i; q < s1; ++q) {
                int v = dst[q] - base;
                if ((unsigned)v < RSZ) { int p = atomicAdd(&cur[v], 1); csr_src[rowptr[base + v] + bi[v] + p] = src[q]; }
            }
        }
    }
}

// ---------------- W -> f16 transposed: wt[c][k] = (f16)W[k][c] ----------------
__global__ void transpose_w(const float* __restrict__ W1, const float* __restrict__ W2,
                            f16* __restrict__ w1t, f16* __restrict__ w2t) {
    int t = blockIdx.x * blockDim.x + threadIdx.x;
    if (t < DIN * DHID) {
        int k = t / DHID, c = t % DHID;
        w1t[c * DIN + k] = (f16)W1[t];
    } else {
        int u = t - DIN * DHID;
        if (u < DHID * DOF) {
            int k = u / DOF, c = u % DOF;
            w2t[c * DHID + k] = (f16)W2[u];
        }
    }
}

// ---------------- MFMA GEMM, BM=128, 2-set/3-tile prefetch (R13 measured-best) ----------------
template<int K, int N, bool A_F32>
__global__ __launch_bounds__(256) void mfma_gemm(const void* __restrict__ Aptr,
                                                 const float* __restrict__ norm,
                                                 const f16* __restrict__ Bt,
                                                 f16* __restrict__ H, int M) {
    constexpr int BM = 128, BN = 128, BK = 32;
    constexpr int NT = K / BK;
    __shared__ __align__(16) f16 smem[BM * BN];      // 32KB

    const int rbase = blockIdx.x * BM;
    const int nbj = blockIdx.y * BN;
    const int tid = threadIdx.x;
    const int l = tid & 63, wid = tid >> 6;
    const int wr = wid >> 1, wc = wid & 1;
    const int fr = l & 15, kg = l >> 4;

    int arow[2], achk[2];
    float ascale[2];
#pragma unroll
    for (int j = 0; j < 2; ++j) {
        int u = tid + j * 256;
        arow[j] = u >> 2; achk[j] = u & 3;
        if (A_F32) {
            int grow = rbase + arow[j];
            ascale[j] = (grow < M) ? norm[grow] : 0.0f;
        }
    }

    struct ABregs {
        float4 a0[2], a1[2];
        f16x8  a16[2];
        f16x8  b[2];
    };

    auto gload = [&](int k0) {
        ABregs r;
#pragma unroll
        for (int j = 0; j < 2; ++j) {
            int grow = rbase + arow[j];
            if (A_F32) {
                if (grow < M) {
                    const float* A = (const float*)Aptr + (long)grow * K + k0 + achk[j] * 8;
                    r.a0[j] = *(const float4*)A;
                    r.a1[j] = *(const float4*)(A + 4);
                } else {
                    r.a0[j] = make_float4(0.f, 0.f, 0.f, 0.f);
                    r.a1[j] = make_float4(0.f, 0.f, 0.f, 0.f);
                }
            } else {
                f16x8 v = {};
                if (grow < M)
                    v = *(const f16x8*)((const f16*)Aptr + (long)grow * K + k0 + achk[j] * 8);
                r.a16[j] = v;
            }
            r.b[j] = *(const f16x8*)(Bt + (long)(nbj + arow[j]) * K + k0 + achk[j] * 8);
        }
        return r;
    };

    auto swrite = [&](int buf, const ABregs& r) {
        f16* As = smem + buf * 8192;
        f16* Bs = As + 4096;
#pragma unroll
        for (int j = 0; j < 2; ++j) {
            f16x8 v;
            if (A_F32) {
                float s = ascale[j];
                v[0] = (f16)(r.a0[j].x * s); v[1] = (f16)(r.a0[j].y * s);
                v[2] = (f16)(r.a0[j].z * s); v[3] = (f16)(r.a0[j].w * s);
                v[4] = (f16)(r.a1[j].x * s); v[5] = (f16)(r.a1[j].y * s);
                v[6] = (f16)(r.a1[j].z * s); v[7] = (f16)(r.a1[j].w * s);
            } else {
                v = r.a16[j];
            }
            int ia = (arow[j] * BK + achk[j] * 8) ^ ((arow[j] & 7) << 3);
            *(f16x8*)&As[ia] = v;
            *(f16x8*)&Bs[ia] = r.b[j];
        }
    };

    f32x4 acc[4][4] = {};

    auto compute = [&](int buf) {
        const f16* As = smem + buf * 8192;
        const f16* Bs = As + 4096;
        f16x8 af[4], bf[4];
#pragma unroll
        for (int m = 0; m < 4; ++m) {
            int row = wr * 64 + m * 16 + fr;
            int ia = (row * BK + kg * 8) ^ ((row & 7) << 3);
            af[m] = *(const f16x8*)&As[ia];
        }
#pragma unroll
        for (int nf = 0; nf < 4; ++nf) {
            int c = wc * 64 + nf * 16 + fr;
            int ib = (c * BK + kg * 8) ^ ((c & 7) << 3);
            bf[nf] = *(const f16x8*)&Bs[ib];
        }
#pragma unroll
        for (int m = 0; m < 4; ++m)
#pragma unroll
            for (int nf = 0; nf < 4; ++nf)
                acc[m][nf] = __builtin_amdgcn_mfma_f32_16x16x32_f16(af[m], bf[nf], acc[m][nf], 0, 0, 0);
    };

    ABregs rb, rc;
    {
        ABregs ra = gload(0);
        swrite(0, ra);
        rb = gload(BK);
        if (NT > 2) rc = gload(2 * BK);
    }

#pragma unroll
    for (int kt = 0; kt < NT; kt += 2) {
        __syncthreads();
        compute(0);
        if (kt + 1 < NT) swrite(1, rb);
        if (kt + 3 < NT) rb = gload((kt + 3) * BK);
        if (kt + 1 < NT) {
            __syncthreads();
            compute(1);
            if (kt + 2 < NT) swrite(0, rc);
            if (kt + 4 < NT) rc = gload((kt + 4) * BK);
        }
    }

    __syncthreads();
#pragma unroll
    for (int m = 0; m < 4; ++m)
#pragma unroll
        for (int nf = 0; nf < 4; ++nf)
#pragma unroll
            for (int i = 0; i < 4; ++i) {
                int row = wr * 64 + m * 16 + (l >> 4) * 4 + i;
                int col = wc * 64 + nf * 16 + (l & 15);
                smem[row * BN + col] = (f16)acc[m][nf][i];
            }
    __syncthreads();
#pragma unroll
    for (int j = 0; j < 8; ++j) {
        int u = tid + j * 256;
        int row = u >> 4, cu = u & 15;
        int grow = rbase + row;
        if (grow < M)
            *(f16x8*)(H + (long)grow * N + nbj + cu * 8) =
                *(const f16x8*)&smem[row * BN + cu * 8];
    }
}

// ---------------- multi-edge vectorized CSR aggregate (16B/lane), fused epilogue ----------------
// One wave per node. LR = F/8 lanes cover one row (f16x8 each); EPW = 64/LR edges
// per wave-load instruction. Full 4-instruction batches unguarded; clamped tail.
// Cross-slot partial sums combined via shfl_xor; slot-0 lanes store the row once.
template<int F, bool RELU, bool FOLD, bool OUT_F16>
__global__ __launch_bounds__(256) void aggregate_vec(const f16* __restrict__ H,
                                                     const int* __restrict__ rowptr,
                                                     const int* __restrict__ csr_src,
                                                     const float* __restrict__ norm_dst,
                                                     const float* __restrict__ norm_src,
                                                     const float* __restrict__ bias,
                                                     void* __restrict__ outp, int n) {
    constexpr int LR = F / 8;          // lanes per row: 32 (F=256), 16 (F=128)
    constexpr int EPW = 64 / LR;       // edges per wave-instr: 2, 4

    const int node = blockIdx.x * 4 + (threadIdx.x >> 6);
    if (node >= n) return;
    const int l = threadIdx.x & 63;
    const int slot = l / LR;           // which edge within the instruction
    const int col = (l & (LR - 1)) * 8;
    const f16* __restrict__ Hc = H + col;

    int k = rowptr[node];
    const int end = rowptr[node + 1];

    float acc[8] = {};
    // full batches: 4 wave-instructions = 4*EPW edges, no guards
    for (; k + 4 * EPW <= end; k += 4 * EPW) {
        int i0 = csr_src[k + slot];
        int i1 = csr_src[k + EPW + slot];
        int i2 = csr_src[k + 2 * EPW + slot];
        int i3 = csr_src[k + 3 * EPW + slot];
        f16x8 v0 = *(const f16x8*)(Hc + (long)i0 * F);
        f16x8 v1 = *(const f16x8*)(Hc + (long)i1 * F);
        f16x8 v2 = *(const f16x8*)(Hc + (long)i2 * F);
        f16x8 v3 = *(const f16x8*)(Hc + (long)i3 * F);
#pragma unroll
        for (int q = 0; q < 8; ++q) acc[q] += (float)v0[q];
#pragma unroll
        for (int q = 0; q < 8; ++q) acc[q] += (float)v1[q];
#pragma unroll
        for (int q = 0; q < 8; ++q) acc[q] += (float)v2[q];
#pragma unroll
        for (int q = 0; q < 8; ++q) acc[q] += (float)v3[q];
    }
    // tail: guarded per wave-instruction (clamped index keeps load in-bounds)
    for (; k < end; k += EPW) {
        int idx = k + slot;
        int ci = min(idx, end - 1);
        int s = csr_src[ci];
        f16x8 v = *(const f16x8*)(Hc + (long)s * F);
        if (idx < end) {
#pragma unroll
            for (int q = 0; q < 8; ++q) acc[q] += (float)v[q];
        }
    }

    // combine slot partial sums (lanes with same col across slots)
#pragma unroll
    for (int o = LR; o < 64; o <<= 1) {
#pragma unroll
        for (int q = 0; q < 8; ++q) acc[q] += __shfl_xor(acc[q], o);
    }

    const float nd = norm_dst[node];
    const float ns = FOLD ? norm_src[node] : 1.0f;
#pragma unroll
    for (int q = 0; q < 8; ++q) {
        float v = acc[q] * nd + bias[col + q];
        if (RELU) v = fmaxf(v, 0.0f);
        acc[q] = v * ns;
    }

    if (slot == 0) {
        if (OUT_F16) {
            f16x8 o;
#pragma unroll
            for (int q = 0; q < 8; ++q) o[q] = (f16)acc[q];
            *(f16x8*)((f16*)outp + (long)node * F + col) = o;
        } else {
            float* op = (float*)outp + (long)node * F + col;
            *(float4*)op = make_float4(acc[0], acc[1], acc[2], acc[3]);
            *(float4*)(op + 4) = make_float4(acc[4], acc[5], acc[6], acc[7]);
        }
    }
}

extern "C" void kernel_launch(void* const* d_in, const int* in_sizes, int n_in,
                              void* d_out, int out_size, void* d_ws, size_t ws_size,
                              hipStream_t stream) {
    const float* features = (const float*)d_in[0];
    const int*   src      = (const int*)d_in[1];
    const int*   dst      = (const int*)d_in[2];
    const float* W1       = (const float*)d_in[3];
    const float* b1       = (const float*)d_in[4];
    const float* W2       = (const float*)d_in[5];
    const float* b2       = (const float*)d_in[6];
    float* out = (float*)d_out;

    const int n = in_sizes[0] / DIN;   // 50000
    const int e = in_sizes[1];         // 800000

    const int ranges = (n + RSZ - 1) >> RB;            // 7
    const size_t cntsz = (size_t)ranges * BPR * RSZ;

    // ---- workspace layout ----
    char* ws = (char*)d_ws;
    size_t off = 0;
    auto alloc = [&](size_t bytes) { size_t o = off; off += (bytes + 255) & ~(size_t)255; return o; };
    size_t o_degi   = alloc((size_t)n * 4);            // deg_in
    size_t o_nsrc   = alloc((size_t)n * 4);            // norm_src
    size_t o_ndst   = alloc((size_t)n * 4);            // norm_dst
    size_t o_rowptr = alloc((size_t)(n + 1) * 4);      // rowptr
    size_t o_part   = alloc((size_t)64 * 4);           // scan partials
    size_t o_csr    = alloc((size_t)e * 4);            // csr_src
    size_t o_cnto   = alloc(cntsz * 4);                // cnt_out
    size_t o_cnti   = alloc(cntsz * 4);                // cnt_in -> base_in
    size_t o_w1t    = alloc((size_t)DIN * DHID * 2);   // W1^T f16
    size_t o_w2t    = alloc((size_t)DHID * DOF * 2);   // W2^T f16
    size_t o_h1     = alloc((size_t)n * DHID * 2);     // h1 f16
    size_t o_x1     = alloc((size_t)n * DHID * 2);     // x1 f16 (pre-scaled by norm_src)
    size_t o_h2     = alloc((size_t)n * DOF * 2);      // h2 f16
    (void)ws_size;

    int*   deg_in   = (int*)(ws + o_degi);
    float* norm_src = (float*)(ws + o_nsrc);
    float* norm_dst = (float*)(ws + o_ndst);
    int*   rowptr   = (int*)(ws + o_rowptr);
    int*   partial  = (int*)(ws + o_part);
    int*   csr_src  = (int*)(ws + o_csr);
    int*   cnt_out  = (int*)(ws + o_cnto);
    int*   cnt_in   = (int*)(ws + o_cnti);
    f16*   w1t      = (f16*)(ws + o_w1t);
    f16*   w2t      = (f16*)(ws + o_w2t);
    f16*   h1       = (f16*)(ws + o_h1);
    f16*   x1       = (f16*)(ws + o_x1);
    f16*   h2       = (f16*)(ws + o_h2);

    // ---- graph preprocessing (no global atomics, no memsets) ----
    const int hblocks = ranges * BPR;                  // 224
    hist_deg<<<hblocks, 256, 0, stream>>>(src, dst, e, cnt_out, cnt_in);
    sum_base<<<(n + 255) / 256, 256, 0, stream>>>(cnt_out, cnt_in, deg_in,
                                                  norm_src, norm_dst, n);
    const int nb = (n + 1023) / 1024;                  // 49
    scan_part<<<nb, 256, 0, stream>>>(deg_in, partial, n);
    scan_offsets<<<1, 64, 0, stream>>>(partial, nb, rowptr, n);
    scan_apply<<<nb, 256, 0, stream>>>(deg_in, partial, rowptr, n);
    fill_csr2<<<hblocks, 256, 0, stream>>>(src, dst, e, rowptr, cnt_in, csr_src);
    transpose_w<<<(DIN * DHID + DHID * DOF + 255) / 256, 256, 0, stream>>>(W1, W2, w1t, w2t);

    const int mtiles = (n + 127) / 128;      // 391
    const int ablocks = (n + 3) / 4;         // 4 nodes (waves) per 256-thr block

    // ---- layer 1 ----
    mfma_gemm<DIN, DHID, true><<<dim3(mtiles, DHID / 128), 256, 0, stream>>>(
        features, norm_src, w1t, h1, n);
    aggregate_vec<DHID, true, true, true><<<ablocks, 256, 0, stream>>>(
        h1, rowptr, csr_src, norm_dst, norm_src, b1, x1, n);

    // ---- layer 2 ----
    mfma_gemm<DHID, DOF, false><<<dim3(mtiles, DOF / 128), 256, 0, stream>>>(
        x1, nullptr, w2t, h2, n);
    aggregate_vec<DOF, false, false, false><<<ablocks, 256, 0, stream>>>(
        h2, rowptr, csr_src, norm_dst, norm_src, b2, out, n);
}